// Round 2
// baseline (442.401 us; speedup 1.0000x reference)
//
#include <hip/hip_runtime.h>
#include <hip/hip_bf16.h>
#include <stdint.h>

#define N_NODES 8192
#define D_FEAT  256

typedef __bf16 bf16x8 __attribute__((ext_vector_type(8)));
typedef float  f32x4  __attribute__((ext_vector_type(4)));

__device__ __forceinline__ void async_copy16(const void* g, void* l) {
  __builtin_amdgcn_global_load_lds(
      (const __attribute__((address_space(1))) uint32_t*)g,
      (__attribute__((address_space(3))) uint32_t*)l,
      16, 0, 0);
}

// ---------------- prep: features -> FT[n][k] bf16, pre-swizzled within 64-elem k-chunks
__global__ void k_prep_ft(const float* __restrict__ F, __bf16* __restrict__ FT) {
  __shared__ float tile[32][33];
  int kb = blockIdx.x * 32;   // k block over 8192
  int nb = blockIdx.y * 32;   // n block over 256
  int tx = threadIdx.x;       // 0..31
  int ty = threadIdx.y;       // 0..7
#pragma unroll
  for (int i = 0; i < 4; ++i) {
    int r = ty + i * 8;
    tile[r][tx] = F[(size_t)(kb + r) * 256 + nb + tx];
  }
  __syncthreads();
#pragma unroll
  for (int i = 0; i < 4; ++i) {
    int n = nb + ty + i * 8;
    int k = kb + tx;
    int e = k & 7, s = (k >> 3) & 7, base = k & ~63;
    int ks = base | ((s ^ (n & 7)) << 3) | e;
    FT[(size_t)n * 8192 + ks] = (__bf16)tile[tx][ty + i * 8];
  }
}

// ---------------- prep: W1 = Wout - Wdh, W2 = -Wdt (bf16), c = bo - bd
__global__ void k_prep_w(const float* __restrict__ Wd, const float* __restrict__ bd,
                         const float* __restrict__ Wo, const float* __restrict__ bo,
                         __bf16* __restrict__ W1, __bf16* __restrict__ W2,
                         float* __restrict__ cvec) {
  int o = blockIdx.x;
  int d = threadIdx.x;
  float w1 = Wo[(size_t)o * 256 + d] - Wd[(size_t)o * 512 + d];
  float w2 = -Wd[(size_t)o * 512 + 256 + d];
  W1[(size_t)o * 256 + d] = (__bf16)w1;
  W2[(size_t)o * 256 + d] = (__bf16)w2;
  if (d == 0) cvec[o] = bo[o] - bd[o];
}

// ---------------- main: fused exp(5*adj) masked-softmax-numerator GEMM + row denominators
// BM=64 rows/WG, KB=64, 8 waves (2x4). Per K-split: output 64x256 fp32 partial,
// or (direct mode, ksplit==1) normalized bf16 tail written in-kernel.
__global__ __launch_bounds__(512)
void k_main(const float* __restrict__ adj, const __bf16* __restrict__ FT,
            float* __restrict__ partial, float* __restrict__ pdenom,
            __bf16* __restrict__ tailbf,
            int kslog, int nk, int direct) {
  __shared__ __align__(16) char lds[40960];  // A: [0,8192)  B: [8192,40960)
  const int tid = threadIdx.x;
  const int bx = blockIdx.x;
  const int sp = bx & ((1 << kslog) - 1);
  const int mtile = bx >> kslog;
  const int r0 = mtile * 64;
  const int kbase = sp * (N_NODES >> kslog);

  const int rowl = tid >> 3;   // 0..63
  const int sl = tid & 7;      // 16B slot 0..7
  const int rg = r0 + rowl;

  const float* ap = adj + (size_t)rg * N_NODES + kbase + sl * 8;
  float4 c0 = *(const float4*)(ap);
  float4 c1 = *(const float4*)(ap + 4);

  float dsum = 0.f;

  f32x4 acc[2][4];
#pragma unroll
  for (int i = 0; i < 2; ++i)
#pragma unroll
    for (int j = 0; j < 4; ++j) acc[i][j] = (f32x4){0.f, 0.f, 0.f, 0.f};

  const int wv = tid >> 6;
  const int lane = tid & 63;
  const int wr = wv >> 2;   // 0..1
  const int wc = wv & 3;    // 0..3
  const int l15 = lane & 15;
  const int q = lane >> 4;

  char* aw = lds + rowl * 128 + ((sl ^ (rowl & 7)) << 4);

  for (int ks = 0; ks < nk; ++ks) {
    __builtin_amdgcn_sched_barrier(0);
    __builtin_amdgcn_s_barrier();   // prev MFMA phase done: LDS reusable
    __builtin_amdgcn_sched_barrier(0);
    // issue async B tile copy: FT[0..255][k0..k0+64) -> ldsB (pre-swizzled in global)
    {
      const size_t kb2 = (size_t)(kbase + ks * 64) * 2;
#pragma unroll
      for (int i = 0; i < 4; ++i) {
        int off = (i * 512 + tid) * 16;
        const char* gsrc = (const char*)FT + (size_t)(off >> 7) * 16384 + kb2 + (off & 127);
        async_copy16(gsrc, lds + 8192 + off);
      }
    }
    __builtin_amdgcn_sched_barrier(0);
    // E = exp(5*adj), diagonal masked; accumulate row denominator; pack bf16
    {
      float ev[8] = {c0.x, c0.y, c0.z, c0.w, c1.x, c1.y, c1.z, c1.w};
      const int kk = kbase + ks * 64 + sl * 8;
      float s8 = 0.f;
      bf16x8 pk;
#pragma unroll
      for (int j = 0; j < 8; ++j) {
        float v = __expf(5.f * ev[j]);
        v = (kk + j == rg) ? 0.f : v;
        s8 += v;
        pk[j] = (__bf16)v;
      }
      dsum += s8;
      *(bf16x8*)aw = pk;   // ds_write_b128, XOR-swizzled slot
    }
    // prefetch next adj tile into registers (stays in flight across barrier)
    {
      int ksn = (ks + 1 < nk) ? (ks + 1) : 0;
      const float* apn = ap + (size_t)ksn * 64;
      c0 = *(const float4*)(apn);
      c1 = *(const float4*)(apn + 4);
    }
    __builtin_amdgcn_sched_barrier(0);
    asm volatile("s_waitcnt vmcnt(2) lgkmcnt(0)" ::: "memory");  // B arrived + A written; adj prefetch outstanding
    __builtin_amdgcn_sched_barrier(0);
    __builtin_amdgcn_s_barrier();
    __builtin_amdgcn_sched_barrier(0);
    // MFMA phase
    {
      bf16x8 af[2][2], bfr[4][2];
#pragma unroll
      for (int rf = 0; rf < 2; ++rf)
#pragma unroll
        for (int kf = 0; kf < 2; ++kf) {
          int row = wr * 32 + rf * 16 + l15;
          int slot = kf * 4 + q;
          af[rf][kf] = *(const bf16x8*)(lds + row * 128 + ((slot ^ (row & 7)) << 4));
        }
#pragma unroll
      for (int cf = 0; cf < 4; ++cf)
#pragma unroll
        for (int kf = 0; kf < 2; ++kf) {
          int nn = wc * 64 + cf * 16 + l15;
          int slot = kf * 4 + q;
          bfr[cf][kf] = *(const bf16x8*)(lds + 8192 + nn * 128 + ((slot ^ (nn & 7)) << 4));
        }
#pragma unroll
      for (int rf = 0; rf < 2; ++rf)
#pragma unroll
        for (int cf = 0; cf < 4; ++cf)
#pragma unroll
          for (int kf = 0; kf < 2; ++kf)
            acc[rf][cf] = __builtin_amdgcn_mfma_f32_16x16x32_bf16(
                af[rf][kf], bfr[cf][kf], acc[rf][cf], 0, 0, 0);
    }
    __builtin_amdgcn_sched_barrier(0);
  }

  // row denominator: 8-lane group reduce (lanes 8k..8k+7 share a row)
  dsum += __shfl_xor(dsum, 1);
  dsum += __shfl_xor(dsum, 2);
  dsum += __shfl_xor(dsum, 4);

  if (direct) {
    // ksplit==1: full row sums available; normalize in-kernel, write bf16 tail.
    float* dn = (float*)lds;
    __syncthreads();               // all MFMA-phase LDS reads retired
    if (sl == 0) dn[rowl] = dsum;
    __syncthreads();
#pragma unroll
    for (int rf = 0; rf < 2; ++rf)
#pragma unroll
      for (int cf = 0; cf < 4; ++cf)
#pragma unroll
        for (int j = 0; j < 4; ++j) {
          int rl = wr * 32 + rf * 16 + q * 4 + j;
          int col = wc * 64 + cf * 16 + l15;
          tailbf[(size_t)(r0 + rl) * D_FEAT + col] = (__bf16)(acc[rf][cf][j] / dn[rl]);
        }
  } else {
    float* pout = partial + (size_t)sp * ((size_t)N_NODES * D_FEAT);
#pragma unroll
    for (int rf = 0; rf < 2; ++rf)
#pragma unroll
      for (int cf = 0; cf < 4; ++cf)
#pragma unroll
        for (int j = 0; j < 4; ++j) {
          int row = r0 + wr * 32 + rf * 16 + q * 4 + j;
          int col = wc * 64 + cf * 16 + l15;
          pout[(size_t)row * D_FEAT + col] = acc[rf][cf][j];
        }
    if (sl == 0) pdenom[(size_t)sp * N_NODES + rg] = dsum;
  }
}

// ---------------- combine K-splits, normalize, convert to bf16
__global__ void k_comb(const float* __restrict__ partial, const float* __restrict__ pden,
                       __bf16* __restrict__ tailbf, int ksplit) {
  int i = blockIdx.x;
  int d = threadIdx.x;
  float v = 0.f, den = 0.f;
  for (int s = 0; s < ksplit; ++s) {
    v += partial[(size_t)s * ((size_t)N_NODES * 256) + (size_t)i * 256 + d];
    den += pden[(size_t)s * N_NODES + i];
  }
  tailbf[(size_t)i * 256 + d] = (__bf16)(v / den);
}

// ---------------- epilogue: out = tanh(F@W1^T + tail@W2^T + c)
__global__ __launch_bounds__(512)
void k_epi(const float* __restrict__ F, const __bf16* __restrict__ tailbf,
           const __bf16* __restrict__ W1, const __bf16* __restrict__ W2,
           const float* __restrict__ cvec, float* __restrict__ out) {
  const int tid = threadIdx.x;
  const int m0 = blockIdx.x * 32;
  const int wv = tid >> 6;      // 0..7 -> 32-col slab
  const int lane = tid & 63;
  const int l15 = lane & 15;
  const int q = lane >> 4;
  const int col0 = wv * 32;

  f32x4 acc[2][2];
#pragma unroll
  for (int i = 0; i < 2; ++i)
#pragma unroll
    for (int j = 0; j < 2; ++j) acc[i][j] = (f32x4){0.f, 0.f, 0.f, 0.f};

#pragma unroll
  for (int kf = 0; kf < 8; ++kf) {
    bf16x8 a1[2], a2[2], b1[2], b2[2];
#pragma unroll
    for (int rf = 0; rf < 2; ++rf) {
      int row = m0 + rf * 16 + l15;
      const float* p = F + (size_t)row * 256 + kf * 32 + q * 8;
      float4 u0 = *(const float4*)p;
      float4 u1 = *(const float4*)(p + 4);
      float tmp[8] = {u0.x, u0.y, u0.z, u0.w, u1.x, u1.y, u1.z, u1.w};
#pragma unroll
      for (int j = 0; j < 8; ++j) a1[rf][j] = (__bf16)tmp[j];
      a2[rf] = *(const bf16x8*)(tailbf + (size_t)row * 256 + kf * 32 + q * 8);
    }
#pragma unroll
    for (int cf = 0; cf < 2; ++cf) {
      int col = col0 + cf * 16 + l15;
      b1[cf] = *(const bf16x8*)(W1 + (size_t)col * 256 + kf * 32 + q * 8);
      b2[cf] = *(const bf16x8*)(W2 + (size_t)col * 256 + kf * 32 + q * 8);
    }
#pragma unroll
    for (int rf = 0; rf < 2; ++rf)
#pragma unroll
      for (int cf = 0; cf < 2; ++cf) {
        acc[rf][cf] = __builtin_amdgcn_mfma_f32_16x16x32_bf16(a1[rf], b1[cf], acc[rf][cf], 0, 0, 0);
        acc[rf][cf] = __builtin_amdgcn_mfma_f32_16x16x32_bf16(a2[rf], b2[cf], acc[rf][cf], 0, 0, 0);
      }
  }
#pragma unroll
  for (int rf = 0; rf < 2; ++rf)
#pragma unroll
    for (int cf = 0; cf < 2; ++cf) {
      int col = col0 + cf * 16 + l15;
      float cb = cvec[col];
#pragma unroll
      for (int j = 0; j < 4; ++j) {
        int row = m0 + rf * 16 + q * 4 + j;
        out[(size_t)row * 256 + col] = tanhf(acc[rf][cf][j] + cb);
      }
    }
}

extern "C" void kernel_launch(void* const* d_in, const int* in_sizes, int n_in,
                              void* d_out, int out_size, void* d_ws, size_t ws_size,
                              hipStream_t stream) {
  (void)in_sizes; (void)n_in; (void)out_size;
  const float* features = (const float*)d_in[0];
  // d_in[1] key_features: unused by the reference
  const float* adj = (const float*)d_in[2];
  const float* Wd  = (const float*)d_in[3];
  const float* bd  = (const float*)d_in[4];
  const float* Wo  = (const float*)d_in[5];
  const float* bo  = (const float*)d_in[6];
  float* out = (float*)d_out;

  char* ws = (char*)d_ws;
  const size_t SZ_FT   = (size_t)256 * 8192 * 2;   // 4 MB
  const size_t SZ_W    = (size_t)256 * 256 * 2;    // 128 KB
  const size_t SZ_C    = 256 * 4;
  const size_t SZ_TAIL = (size_t)8192 * 256 * 2;   // 4 MB
  const size_t SZ_DEN  = (size_t)4 * 8192 * 4;     // up to 4 splits
  const size_t SZ_P1   = (size_t)8192 * 256 * 4;   // 8 MB per split

  const size_t offFT = 0;
  const size_t offW1 = offFT + SZ_FT;
  const size_t offW2 = offW1 + SZ_W;
  const size_t offC  = offW2 + SZ_W;
  const size_t offT  = offC + SZ_C;
  const size_t offD  = offT + SZ_TAIL;
  const size_t offP  = offD + SZ_DEN;

  int ksplit;
  if      (ws_size >= offP + 4 * SZ_P1) ksplit = 4;   // grid 512 = 2 blocks/CU
  else if (ws_size >= offP + 2 * SZ_P1) ksplit = 2;
  else if (ws_size >= offP + 1 * SZ_P1) ksplit = 1;
  else                                  ksplit = 0;   // direct mode (no partial)
  int direct = (ksplit == 0) ? 1 : 0;
  int kseff  = direct ? 1 : ksplit;
  int kslog  = (kseff == 4) ? 2 : (kseff == 2 ? 1 : 0);
  int nk     = (N_NODES / kseff) / 64;

  __bf16* FT     = (__bf16*)(ws + offFT);
  __bf16* W1     = (__bf16*)(ws + offW1);
  __bf16* W2     = (__bf16*)(ws + offW2);
  float*  cvec   = (float*)(ws + offC);
  __bf16* tailbf = (__bf16*)(ws + offT);
  float*  pden   = (float*)(ws + offD);
  float*  part   = (float*)(ws + offP);

  k_prep_ft<<<dim3(256, 8), dim3(32, 8), 0, stream>>>(features, FT);
  k_prep_w<<<256, 256, 0, stream>>>(Wd, bd, Wo, bo, W1, W2, cvec);
  k_main<<<128 * kseff, 512, 0, stream>>>(adj, FT, part, pden, tailbf, kslog, nk, direct);
  if (!direct)
    k_comb<<<8192, 256, 0, stream>>>(part, pden, tailbf, kseff);
  k_epi<<<256, 512, 0, stream>>>(features, tailbf, W1, W2, cvec, out);
}

// Round 8
// 434.721 us; speedup vs baseline: 1.0177x; 1.0177x over previous
//
#include <hip/hip_runtime.h>
#include <hip/hip_bf16.h>
#include <stdint.h>

#define N_NODES 8192
#define D_FEAT  256

typedef __bf16 bf16x8 __attribute__((ext_vector_type(8)));
typedef float  f32x4  __attribute__((ext_vector_type(4)));

__device__ __forceinline__ void async_copy16(const void* g, void* l) {
  __builtin_amdgcn_global_load_lds(
      (const __attribute__((address_space(1))) uint32_t*)g,
      (__attribute__((address_space(3))) uint32_t*)l,
      16, 0, 0);
}

// ---------------- prep: features -> FT[n][k] bf16, pre-swizzled within 64-elem k-chunks
__global__ void k_prep_ft(const float* __restrict__ F, __bf16* __restrict__ FT) {
  __shared__ float tile[32][33];
  int kb = blockIdx.x * 32;   // k block over 8192
  int nb = blockIdx.y * 32;   // n block over 256
  int tx = threadIdx.x;       // 0..31
  int ty = threadIdx.y;       // 0..7
#pragma unroll
  for (int i = 0; i < 4; ++i) {
    int r = ty + i * 8;
    tile[r][tx] = F[(size_t)(kb + r) * 256 + nb + tx];
  }
  __syncthreads();
#pragma unroll
  for (int i = 0; i < 4; ++i) {
    int n = nb + ty + i * 8;
    int k = kb + tx;
    int e = k & 7, s = (k >> 3) & 7, base = k & ~63;
    int ks = base | ((s ^ (n & 7)) << 3) | e;
    FT[(size_t)n * 8192 + ks] = (__bf16)tile[tx][ty + i * 8];
  }
}

// ---------------- prep: W1 = Wout - Wdh, W2 = -Wdt (bf16), c = bo - bd
__global__ void k_prep_w(const float* __restrict__ Wd, const float* __restrict__ bd,
                         const float* __restrict__ Wo, const float* __restrict__ bo,
                         __bf16* __restrict__ W1, __bf16* __restrict__ W2,
                         float* __restrict__ cvec) {
  int o = blockIdx.x;
  int d = threadIdx.x;
  float w1 = Wo[(size_t)o * 256 + d] - Wd[(size_t)o * 512 + d];
  float w2 = -Wd[(size_t)o * 512 + 256 + d];
  W1[(size_t)o * 256 + d] = (__bf16)w1;
  W2[(size_t)o * 256 + d] = (__bf16)w2;
  if (d == 0) cvec[o] = bo[o] - bd[o];
}

// ---------------- main: fused exp(5*adj) masked-softmax-numerator GEMM + row denominators
// BM=64 rows/WG, KB=64, 8 waves (2x4). Single barrier per K-step, A+B double-buffered LDS.
// VMEM issue order pinned by sched_barrier(0): [B-DMA x4] ... [adj prefetch x2] per iter,
// so vmcnt(2) always == "B for this step landed; adj prefetch may fly".
__global__ __launch_bounds__(512, 4)
void k_main(const float* __restrict__ adj, const __bf16* __restrict__ FT,
            float* __restrict__ partial, float* __restrict__ pdenom,
            __bf16* __restrict__ tailbf,
            int kslog, int nk, int direct) {
  // A bufs: [0,8192),[8192,16384)  B bufs: [16384,49152),[49152,81920)
  __shared__ __align__(16) char lds[81920];
  const int tid = threadIdx.x;
  const int bx = blockIdx.x;
  const int sp = bx & ((1 << kslog) - 1);
  const int mtile = bx >> kslog;
  const int r0 = mtile * 64;
  const int kbase = sp * (N_NODES >> kslog);

  const int rowl = tid >> 3;   // 0..63
  const int sl = tid & 7;      // 16B slot 0..7
  const int rg = r0 + rowl;

  const float* ap = adj + (size_t)rg * N_NODES + kbase + sl * 8;

  float dsum = 0.f;

  f32x4 acc[2][4];
#pragma unroll
  for (int i = 0; i < 2; ++i)
#pragma unroll
    for (int j = 0; j < 4; ++j) acc[i][j] = (f32x4){0.f, 0.f, 0.f, 0.f};

  const int wv = tid >> 6;
  const int lane = tid & 63;
  const int wr = wv >> 2;   // 0..1
  const int wc = wv & 3;    // 0..3
  const int l15 = lane & 15;
  const int q = lane >> 4;

  const int awoff = rowl * 128 + ((sl ^ (rowl & 7)) << 4);

  auto issueB = [&](int ks, int bufsel) {
    const size_t kb2 = (size_t)(kbase + ks * 64) * 2;
    char* dst = lds + 16384 + bufsel * 32768;
#pragma unroll
    for (int i = 0; i < 4; ++i) {
      int off = (i * 512 + tid) * 16;
      const char* gsrc = (const char*)FT + (size_t)(off >> 7) * 16384 + kb2 + (off & 127);
      async_copy16(gsrc, dst + off);
    }
  };

  // --- prologue: adj(0) regs -> exp -> A(0); B(0) DMA; adj(1) prefetch
  float4 c0 = *(const float4*)(ap);
  float4 c1 = *(const float4*)(ap + 4);
  __builtin_amdgcn_sched_barrier(0);
  issueB(0, 0);                       // VMEM order: [c-init x2][B0 x4]
  __builtin_amdgcn_sched_barrier(0);
  {
    float ev[8] = {c0.x, c0.y, c0.z, c0.w, c1.x, c1.y, c1.z, c1.w};
    const int kk = kbase + sl * 8;
    float s8 = 0.f;
    bf16x8 pk;
#pragma unroll
    for (int j = 0; j < 8; ++j) {
      float v = __expf(5.f * ev[j]);
      v = (kk + j == rg) ? 0.f : v;
      s8 += v;
      pk[j] = (__bf16)v;
    }
    dsum += s8;
    *(bf16x8*)(lds + awoff) = pk;     // A(0) -> buf 0
  }
  __builtin_amdgcn_sched_barrier(0);
  {  // adj tile 1 prefetch (last VMEM issued in prologue)
    int t = (1 < nk) ? 1 : 0;
    const float* apn = ap + (size_t)t * 64;
    c0 = *(const float4*)(apn);
    c1 = *(const float4*)(apn + 4);
  }
  __builtin_amdgcn_sched_barrier(0);

  for (int i = 0; i < nk; ++i) {
    const int cur = i & 1, nxt = cur ^ 1;
    // entry outstanding VMEM: [B(i) x4 oldest][adj(i+1) x2 newest]
    asm volatile("s_waitcnt vmcnt(2) lgkmcnt(0)" ::: "memory");
    __builtin_amdgcn_sched_barrier(0);
    __builtin_amdgcn_s_barrier();
    __builtin_amdgcn_sched_barrier(0);

    // issue B(i+1) DMA into alternate buffer (wrapped on last iter: uniform counts)
    issueB((i + 1 < nk) ? i + 1 : 0, nxt);
    __builtin_amdgcn_sched_barrier(0);

    // MFMA on A(i),B(i)  +  exp/pack/ds_write A(i+1) — free to co-schedule
    {
      const char* bufAc = lds + cur * 8192;
      const char* bufBc = lds + 16384 + cur * 32768;
      __builtin_amdgcn_s_setprio(1);
#pragma unroll
      for (int kf = 0; kf < 2; ++kf) {
        const int slot = kf * 4 + q;
        bf16x8 af[2], bfr[4];
#pragma unroll
        for (int rf = 0; rf < 2; ++rf) {
          int row = wr * 32 + rf * 16 + l15;
          af[rf] = *(const bf16x8*)(bufAc + row * 128 + ((slot ^ (row & 7)) << 4));
        }
#pragma unroll
        for (int cf = 0; cf < 4; ++cf) {
          int nn = wc * 64 + cf * 16 + l15;
          bfr[cf] = *(const bf16x8*)(bufBc + nn * 128 + ((slot ^ (nn & 7)) << 4));
        }
#pragma unroll
        for (int rf = 0; rf < 2; ++rf)
#pragma unroll
          for (int cf = 0; cf < 4; ++cf)
            acc[rf][cf] = __builtin_amdgcn_mfma_f32_16x16x32_bf16(
                af[rf], bfr[cf], acc[rf][cf], 0, 0, 0);
      }
      __builtin_amdgcn_s_setprio(0);
    }
    if (i + 1 < nk) {
      float ev[8] = {c0.x, c0.y, c0.z, c0.w, c1.x, c1.y, c1.z, c1.w};
      const int kk = kbase + (i + 1) * 64 + sl * 8;
      float s8 = 0.f;
      bf16x8 pk;
#pragma unroll
      for (int j = 0; j < 8; ++j) {
        float v = __expf(5.f * ev[j]);
        v = (kk + j == rg) ? 0.f : v;
        s8 += v;
        pk[j] = (__bf16)v;
      }
      dsum += s8;
      *(bf16x8*)(lds + nxt * 8192 + awoff) = pk;
    }
    __builtin_amdgcn_sched_barrier(0);

    // adj register prefetch for tile i+2 (always 2 loads, wrapped: uniform vmcnt)
    {
      int t = i + 2;
      if (t >= nk) t -= nk;
      const float* apn = ap + (size_t)t * 64;
      c0 = *(const float4*)(apn);
      c1 = *(const float4*)(apn + 4);
    }
    __builtin_amdgcn_sched_barrier(0);
  }

  // drain wrapped B-DMA + adj prefetch before LDS reuse / endpgm (DMA into a
  // retired workgroup's LDS would corrupt a successor workgroup)
  asm volatile("s_waitcnt vmcnt(0)" ::: "memory");
  __builtin_amdgcn_sched_barrier(0);

  // row denominator: 8-lane group reduce (lanes 8k..8k+7 share a row)
  dsum += __shfl_xor(dsum, 1);
  dsum += __shfl_xor(dsum, 2);
  dsum += __shfl_xor(dsum, 4);

  if (direct) {
    float* dn = (float*)lds;
    __syncthreads();
    if (sl == 0) dn[rowl] = dsum;
    __syncthreads();
#pragma unroll
    for (int rf = 0; rf < 2; ++rf)
#pragma unroll
      for (int cf = 0; cf < 4; ++cf)
#pragma unroll
        for (int j = 0; j < 4; ++j) {
          int rl = wr * 32 + rf * 16 + q * 4 + j;
          int col = wc * 64 + cf * 16 + l15;
          tailbf[(size_t)(r0 + rl) * D_FEAT + col] = (__bf16)(acc[rf][cf][j] / dn[rl]);
        }
  } else {
    float* pout = partial + (size_t)sp * ((size_t)N_NODES * D_FEAT);
#pragma unroll
    for (int rf = 0; rf < 2; ++rf)
#pragma unroll
      for (int cf = 0; cf < 4; ++cf)
#pragma unroll
        for (int j = 0; j < 4; ++j) {
          int row = r0 + wr * 32 + rf * 16 + q * 4 + j;
          int col = wc * 64 + cf * 16 + l15;
          pout[(size_t)row * D_FEAT + col] = acc[rf][cf][j];
        }
    if (sl == 0) pdenom[(size_t)sp * N_NODES + rg] = dsum;
  }
}

// ---------------- combine K-splits, normalize, convert to bf16 (float4 path)
// grid: 2048 blocks x 256 thr; each thread handles one float4 (4 cols of one row)
__global__ void k_comb(const float* __restrict__ partial, const float* __restrict__ pden,
                       __bf16* __restrict__ tailbf, int ksplit) {
  int g = blockIdx.x * 256 + threadIdx.x;      // float4 index over N*256/4
  int row = g >> 6;                             // 64 float4 per row
  int c4 = (g & 63) * 4;
  float4 v = {0.f, 0.f, 0.f, 0.f};
  float den = 0.f;
  for (int s = 0; s < ksplit; ++s) {
    const float* p = partial + (size_t)s * ((size_t)N_NODES * 256) + (size_t)row * 256 + c4;
    float4 u = *(const float4*)p;
    v.x += u.x; v.y += u.y; v.z += u.z; v.w += u.w;
    den += pden[(size_t)s * N_NODES + row];
  }
  float inv = 1.f / den;
  __bf16* o = tailbf + (size_t)row * 256 + c4;
  o[0] = (__bf16)(v.x * inv);
  o[1] = (__bf16)(v.y * inv);
  o[2] = (__bf16)(v.z * inv);
  o[3] = (__bf16)(v.w * inv);
}

// ---------------- epilogue: out = tanh(F@W1^T + tail@W2^T + c)
__global__ __launch_bounds__(512)
void k_epi(const float* __restrict__ F, const __bf16* __restrict__ tailbf,
           const __bf16* __restrict__ W1, const __bf16* __restrict__ W2,
           const float* __restrict__ cvec, float* __restrict__ out) {
  const int tid = threadIdx.x;
  const int m0 = blockIdx.x * 32;
  const int wv = tid >> 6;      // 0..7 -> 32-col slab
  const int lane = tid & 63;
  const int l15 = lane & 15;
  const int q = lane >> 4;
  const int col0 = wv * 32;

  f32x4 acc[2][2];
#pragma unroll
  for (int i = 0; i < 2; ++i)
#pragma unroll
    for (int j = 0; j < 2; ++j) acc[i][j] = (f32x4){0.f, 0.f, 0.f, 0.f};

#pragma unroll
  for (int kf = 0; kf < 8; ++kf) {
    bf16x8 a1[2], a2[2], b1[2], b2[2];
#pragma unroll
    for (int rf = 0; rf < 2; ++rf) {
      int row = m0 + rf * 16 + l15;
      const float* p = F + (size_t)row * 256 + kf * 32 + q * 8;
      float4 u0 = *(const float4*)p;
      float4 u1 = *(const float4*)(p + 4);
      float tmp[8] = {u0.x, u0.y, u0.z, u0.w, u1.x, u1.y, u1.z, u1.w};
#pragma unroll
      for (int j = 0; j < 8; ++j) a1[rf][j] = (__bf16)tmp[j];
      a2[rf] = *(const bf16x8*)(tailbf + (size_t)row * 256 + kf * 32 + q * 8);
    }
#pragma unroll
    for (int cf = 0; cf < 2; ++cf) {
      int col = col0 + cf * 16 + l15;
      b1[cf] = *(const bf16x8*)(W1 + (size_t)col * 256 + kf * 32 + q * 8);
      b2[cf] = *(const bf16x8*)(W2 + (size_t)col * 256 + kf * 32 + q * 8);
    }
#pragma unroll
    for (int rf = 0; rf < 2; ++rf)
#pragma unroll
      for (int cf = 0; cf < 2; ++cf) {
        acc[rf][cf] = __builtin_amdgcn_mfma_f32_16x16x32_bf16(a1[rf], b1[cf], acc[rf][cf], 0, 0, 0);
        acc[rf][cf] = __builtin_amdgcn_mfma_f32_16x16x32_bf16(a2[rf], b2[cf], acc[rf][cf], 0, 0, 0);
      }
  }
#pragma unroll
  for (int rf = 0; rf < 2; ++rf)
#pragma unroll
    for (int cf = 0; cf < 2; ++cf) {
      int col = col0 + cf * 16 + l15;
      float cb = cvec[col];
#pragma unroll
      for (int j = 0; j < 4; ++j) {
        int row = m0 + rf * 16 + q * 4 + j;
        out[(size_t)row * 256 + col] = tanhf(acc[rf][cf][j] + cb);
      }
    }
}

extern "C" void kernel_launch(void* const* d_in, const int* in_sizes, int n_in,
                              void* d_out, int out_size, void* d_ws, size_t ws_size,
                              hipStream_t stream) {
  (void)in_sizes; (void)n_in; (void)out_size;
  const float* features = (const float*)d_in[0];
  // d_in[1] key_features: unused by the reference
  const float* adj = (const float*)d_in[2];
  const float* Wd  = (const float*)d_in[3];
  const float* bd  = (const float*)d_in[4];
  const float* Wo  = (const float*)d_in[5];
  const float* bo  = (const float*)d_in[6];
  float* out = (float*)d_out;

  char* ws = (char*)d_ws;
  const size_t SZ_FT   = (size_t)256 * 8192 * 2;   // 4 MB
  const size_t SZ_W    = (size_t)256 * 256 * 2;    // 128 KB
  const size_t SZ_C    = 256 * 4;
  const size_t SZ_TAIL = (size_t)8192 * 256 * 2;   // 4 MB
  const size_t SZ_DEN  = (size_t)4 * 8192 * 4;     // up to 4 splits
  const size_t SZ_P1   = (size_t)8192 * 256 * 4;   // 8 MB per split

  const size_t offFT = 0;
  const size_t offW1 = offFT + SZ_FT;
  const size_t offW2 = offW1 + SZ_W;
  const size_t offC  = offW2 + SZ_W;
  const size_t offT  = offC + SZ_C;
  const size_t offD  = offT + SZ_TAIL;
  const size_t offP  = offD + SZ_DEN;

  int ksplit;
  if      (ws_size >= offP + 4 * SZ_P1) ksplit = 4;   // grid 512 = 2 blocks/CU
  else if (ws_size >= offP + 2 * SZ_P1) ksplit = 2;
  else if (ws_size >= offP + 1 * SZ_P1) ksplit = 1;
  else                                  ksplit = 0;   // direct mode (no partial)
  int direct = (ksplit == 0) ? 1 : 0;
  int kseff  = direct ? 1 : ksplit;
  int kslog  = (kseff == 4) ? 2 : (kseff == 2 ? 1 : 0);
  int nk     = (N_NODES / kseff) / 64;

  __bf16* FT     = (__bf16*)(ws + offFT);
  __bf16* W1     = (__bf16*)(ws + offW1);
  __bf16* W2     = (__bf16*)(ws + offW2);
  float*  cvec   = (float*)(ws + offC);
  __bf16* tailbf = (__bf16*)(ws + offT);
  float*  pden   = (float*)(ws + offD);
  float*  part   = (float*)(ws + offP);

  k_prep_ft<<<dim3(256, 8), dim3(32, 8), 0, stream>>>(features, FT);
  k_prep_w<<<256, 256, 0, stream>>>(Wd, bd, Wo, bo, W1, W2, cvec);
  k_main<<<128 * kseff, 512, 0, stream>>>(adj, FT, part, pden, tailbf, kslog, nk, direct);
  if (!direct)
    k_comb<<<2048, 256, 0, stream>>>(part, pden, tailbf, kseff);
  k_epi<<<256, 512, 0, stream>>>(features, tailbf, W1, W2, cvec, out);
}